// Round 1
// baseline (209.356 us; speedup 1.0000x reference)
//
#include <hip/hip_runtime.h>

// PSU LIF: V_t = b*V_{t-1} + x_t ; R_t = b*R_{t-1} + sigmoid(V_t)
// out0 = (V - R - 1 > 0) ? 1 : 0, out1 = V.   x:[16,1024,1024] f32, beta:[1024] f32.
// One thread per (batch, h) sequence; serial over T with register-double-buffered
// prefetch (32 loads in flight) to hide HBM latency at ~1 wave/CU occupancy.
// f64 accumulators to keep the hard spike threshold decision accurate.

#define BB 16
#define TT 1024
#define HH 1024
#define UNR 32

__global__ __launch_bounds__(64) void lif_scan(const float* __restrict__ x,
                                               const float* __restrict__ beta,
                                               float* __restrict__ out_spike,
                                               float* __restrict__ out_v) {
    const int tid = blockIdx.x * blockDim.x + threadIdx.x;   // 0..16383
    const int b = tid >> 10;
    const int h = tid & (HH - 1);

    const float bf = fminf(fmaxf(beta[h], 0.0f), 1.0f);
    const double bd = (double)bf;

    const size_t base = (size_t)b * TT * HH + (size_t)h;
    const float* __restrict__ xp = x + base;
    float* __restrict__ sp = out_spike + base;
    float* __restrict__ vp = out_v + base;

    double V = 0.0, R = 0.0;

    float xbuf[UNR];
#pragma unroll
    for (int i = 0; i < UNR; ++i) xbuf[i] = xp[(size_t)i * HH];

#pragma unroll 1
    for (int t0 = 0; t0 < TT; t0 += UNR) {
        float xnext[UNR];
        const bool more = (t0 + UNR) < TT;
        if (more) {
#pragma unroll
            for (int i = 0; i < UNR; ++i)
                xnext[i] = xp[(size_t)(t0 + UNR + i) * HH];
        }
#pragma unroll
        for (int i = 0; i < UNR; ++i) {
            V = fma(bd, V, (double)xbuf[i]);
            const float vf = (float)V;
            const float s = 1.0f / (1.0f + __expf(-vf));
            R = fma(bd, R, (double)s);
            const double d = V - R;
            const size_t off = (size_t)(t0 + i) * HH;
            sp[off] = (d > 1.0) ? 1.0f : 0.0f;
            vp[off] = vf;
        }
        if (more) {
#pragma unroll
            for (int i = 0; i < UNR; ++i) xbuf[i] = xnext[i];
        }
    }
}

extern "C" void kernel_launch(void* const* d_in, const int* in_sizes, int n_in,
                              void* d_out, int out_size, void* d_ws, size_t ws_size,
                              hipStream_t stream) {
    const float* x = (const float*)d_in[0];
    const float* beta = (const float*)d_in[1];
    float* out = (float*)d_out;
    float* out_spike = out;                                  // [16,1024,1024]
    float* out_v = out + (size_t)BB * TT * HH;               // [16,1024,1024]

    const int total_threads = BB * HH;                       // 16384
    const int block = 64;
    const int grid = total_threads / block;                  // 256 blocks, 1 wave each
    lif_scan<<<grid, block, 0, stream>>>(x, beta, out_spike, out_v);
}